// Round 6
// baseline (124.425 us; speedup 1.0000x reference)
//
#include <hip/hip_runtime.h>
#include <hip/hip_bf16.h>

#define N 8192
#define D 128
#define JC 16                // j-chunks
#define BM 256               // rows per block (4 waves x 64 rows)
#define NRB (N / BM)         // 32 row-blocks
#define JCH (N / JC)         // 512 cols per chunk
#define BJ 64                // j-cols per LDS tile
#define NT (JCH / BJ)        // 8 tiles per sweep
#define NLBL 100             // labels in [0,100)
#define LCH 128              // labelsum blocks
#define LR 64                // rows per labelsum block

#define K1F 14.426950408889634f    // 10 * log2(e)
#define K0F (-14.426950408889634f)

#if __has_builtin(__builtin_amdgcn_exp2f)
#define EXP2(x) __builtin_amdgcn_exp2f(x)
#else
#define EXP2(x) exp2f(x)
#endif

typedef __attribute__((ext_vector_type(8))) short bf16x8;
typedef __attribute__((ext_vector_type(4))) float f32x4;

// ---------------- Stage 0: row-normalize z -> bf16 zn, plus self-dot d_ii ----
__global__ __launch_bounds__(256) void znorm_kernel(const float* __restrict__ z,
                                                    ushort* __restrict__ zn,
                                                    float* __restrict__ dii) {
    const int wid  = threadIdx.x >> 6;
    const int lane = threadIdx.x & 63;
    const int row  = blockIdx.x * 4 + wid;       // grid = N/4 blocks
    const float2 v = reinterpret_cast<const float2*>(z + (size_t)row * D)[lane];
    float ss = v.x * v.x + v.y * v.y;
    #pragma unroll
    for (int m = 1; m < 64; m <<= 1) ss += __shfl_xor(ss, m);
    const float inv = 1.0f / fmaxf(sqrtf(ss), 1e-8f);
    __hip_bfloat16 b0 = __float2bfloat16(v.x * inv);
    __hip_bfloat16 b1 = __float2bfloat16(v.y * inv);
    ushort2 o;
    o.x = *reinterpret_cast<ushort*>(&b0);
    o.y = *reinterpret_cast<ushort*>(&b1);
    reinterpret_cast<ushort2*>(zn + (size_t)row * D)[lane] = o;
    const float f0 = __bfloat162float(b0), f1 = __bfloat162float(b1);
    float s2 = f0 * f0 + f1 * f1;
    #pragma unroll
    for (int m = 1; m < 64; m <<= 1) s2 += __shfl_xor(s2, m);
    if (lane == 0) dii[row] = s2;
}

// ---------------- Stage 0b: per-label sums + histogram (deterministic) ------
__global__ __launch_bounds__(256) void labelsum_kernel(const ushort* __restrict__ zn,
                                                       const int* __restrict__ y,
                                                       float* __restrict__ tpart,
                                                       float* __restrict__ cpart) {
    __shared__ float tl[2][NLBL][D];   // 102.4 KB
    __shared__ float ch[2][128];
    __shared__ int   ly[LR];
    const int h = threadIdx.x >> 7;
    const int d = threadIdx.x & 127;
    for (int c = 0; c < NLBL; ++c) tl[h][c][d] = 0.0f;
    if (threadIdx.x < LR) ly[threadIdx.x] = y[blockIdx.x * LR + threadIdx.x];
    __syncthreads();
    const int j0 = blockIdx.x * LR + h * 32;
    float cl = 0.0f;
    for (int j = 0; j < 32; ++j) {
        const int c = ly[h * 32 + j];
        __hip_bfloat16 hb;
        *reinterpret_cast<ushort*>(&hb) = zn[(size_t)(j0 + j) * D + d];
        tl[h][c][d] += __bfloat162float(hb);      // exclusive column: no race
        cl += (c == d) ? 1.0f : 0.0f;
    }
    ch[h][d] = cl;
    __syncthreads();
    const float* t0 = &tl[0][0][0];
    for (int idx = threadIdx.x; idx < NLBL * D; idx += 256)
        tpart[(size_t)blockIdx.x * NLBL * D + idx] = t0[idx] + t0[NLBL * D + idx];
    if (threadIdx.x < NLBL)
        cpart[blockIdx.x * NLBL + threadIdx.x] = ch[0][threadIdx.x] + ch[1][threadIdx.x];
}

// ---------------- Stage 0c: reduce partials (parallel over outputs) ---------
__global__ __launch_bounds__(256) void reduce_t_kernel(const float* __restrict__ tpart,
                                                       const float* __restrict__ cpart,
                                                       float* __restrict__ t,
                                                       float* __restrict__ cnt) {
    if (blockIdx.x < NLBL * D / 64) {
        __shared__ float s4[4][64];
        const int o  = blockIdx.x * 64 + (threadIdx.x & 63);
        const int sl = threadIdx.x >> 6;           // 4 slices x 32 chunks
        float s = 0.0f;
        #pragma unroll 8
        for (int b = sl * (LCH / 4); b < (sl + 1) * (LCH / 4); ++b)
            s += tpart[(size_t)b * NLBL * D + o];
        s4[sl][threadIdx.x & 63] = s;
        __syncthreads();
        if (threadIdx.x < 64)
            t[blockIdx.x * 64 + threadIdx.x] = s4[0][threadIdx.x] + s4[1][threadIdx.x] +
                                               s4[2][threadIdx.x] + s4[3][threadIdx.x];
    } else {
        const int c = threadIdx.x;
        if (c < NLBL) {
            float s = 0.0f;
            for (int b = 0; b < LCH; ++b) s += cpart[b * NLBL + c];
            cnt[c] = s;
        }
    }
}

// ---------------- Stage 1: LDS double-buffered streaming MFMA ----------------
// Per block: 256 rows (4 waves x 64), sweep 8 tiles of 64 j-cols. B-tile staged
// once per block: global->regs issued BEFORE compute (latency hides under 64
// MFMAs), swizzled ds_write AFTER compute, barrier per tile (T3-minimum).
__global__ __launch_bounds__(256, 3) void supcon_main(const ushort* __restrict__ zn,
                                                      float* __restrict__ pZ) {
    __shared__ ushort Bsm[2][BJ * D];   // 2 x 16 KB
    const int wid  = threadIdx.x >> 6;
    const int lane = threadIdx.x & 63;
    const int g    = lane >> 4;      // 0..3
    const int lj   = lane & 15;
    const int rowBlk = blockIdx.x % NRB;
    const int chunk  = blockIdx.x / NRB;
    const int rowBase = rowBlk * BM + wid * 64;   // this wave's 64 rows
    const int j0 = chunk * JCH;

    // staging geometry: wave stages tile rows [wid*16, wid*16+16)
    // call c: lane handles tile row trc + c*4, 16B slot sl (linear global read)
    const int trc = wid * 16 + (lane >> 4);
    const int sl  = lane & 15;

    // A fragments: 4 M-tiles x 4 K-steps (64 VGPR)
    bf16x8 a[4][4];
    #pragma unroll
    for (int m = 0; m < 4; ++m) {
        const ushort* rp = zn + (size_t)(rowBase + m * 16 + lj) * D;
        #pragma unroll
        for (int s = 0; s < 4; ++s)
            a[m][s] = *reinterpret_cast<const bf16x8*>(rp + s * 32 + g * 8);
    }

    float Z[4][4];
    #pragma unroll
    for (int m = 0; m < 4; ++m)
        #pragma unroll
        for (int r = 0; r < 4; ++r) Z[m][r] = 0.0f;

    // prologue: stage tile 0 into Bsm[0] (XOR-swizzled slots: slot ^= row&7)
    bf16x8 st[4];
    #pragma unroll
    for (int c = 0; c < 4; ++c)
        st[c] = *reinterpret_cast<const bf16x8*>(
            zn + (size_t)(j0 + trc + c * 4) * D + sl * 8);
    #pragma unroll
    for (int c = 0; c < 4; ++c) {
        const int tr = trc + c * 4;
        *reinterpret_cast<bf16x8*>(&Bsm[0][tr * D + ((sl ^ (tr & 7)) * 8)]) = st[c];
    }
    __syncthreads();

    const f32x4 zero4 = {0.f, 0.f, 0.f, 0.f};
    #pragma unroll 2
    for (int t = 0; t < NT; ++t) {
        const int cur = t & 1;
        // issue next tile's global loads (consumed after compute)
        if (t + 1 < NT) {
            #pragma unroll
            for (int c = 0; c < 4; ++c)
                st[c] = *reinterpret_cast<const bf16x8*>(
                    zn + (size_t)(j0 + (t + 1) * BJ + trc + c * 4) * D + sl * 8);
        }
        // compute from Bsm[cur]
        #pragma unroll
        for (int jt = 0; jt < 4; ++jt) {
            const int br = jt * 16 + lj;
            const int bx = br & 7;
            bf16x8 b[4];
            #pragma unroll
            for (int s = 0; s < 4; ++s)
                b[s] = *reinterpret_cast<const bf16x8*>(
                    &Bsm[cur][br * D + (((s * 4 + g) ^ bx) * 8)]);
            #pragma unroll
            for (int m = 0; m < 4; ++m) {
                f32x4 acc = zero4;
                #pragma unroll
                for (int s = 0; s < 4; ++s)
                    acc = __builtin_amdgcn_mfma_f32_16x16x32_bf16(a[m][s], b[s], acc, 0, 0, 0);
                #pragma unroll
                for (int r = 0; r < 4; ++r)
                    Z[m][r] += EXP2(fmaf(acc[r], K1F, K0F));   // exp(10*dot-10)
            }
        }
        // write staged regs into the other buffer (reads of it finished last iter)
        if (t + 1 < NT) {
            #pragma unroll
            for (int c = 0; c < 4; ++c) {
                const int tr = trc + c * 4;
                *reinterpret_cast<bf16x8*>(
                    &Bsm[cur ^ 1][tr * D + ((sl ^ (tr & 7)) * 8)]) = st[c];
            }
        }
        __syncthreads();
    }

    // reduce the 16 cols within each lane group
    #pragma unroll
    for (int m = 0; m < 4; ++m)
        #pragma unroll
        for (int r = 0; r < 4; ++r)
            #pragma unroll
            for (int mk = 1; mk < 16; mk <<= 1)
                Z[m][r] += __shfl_xor(Z[m][r], mk);

    if (lj == 0) {
        #pragma unroll
        for (int m = 0; m < 4; ++m)
            #pragma unroll
            for (int r = 0; r < 4; ++r)
                pZ[chunk * N + rowBase + m * 16 + g * 4 + r] = Z[m][r];
    }
}

// ---------------- Stage 2: finalize loss ----------------
__global__ __launch_bounds__(256) void supcon_finalize(const ushort* __restrict__ zn,
                                                       const int* __restrict__ y,
                                                       const float* __restrict__ pZ,
                                                       const float* __restrict__ dii,
                                                       const float* __restrict__ t,
                                                       const float* __restrict__ cnt,
                                                       float* __restrict__ out) {
    const int wid  = threadIdx.x >> 6;
    const int lane = threadIdx.x & 63;
    const int row  = blockIdx.x * 4 + wid;
    const int c    = y[row];
    const ushort2 u = reinterpret_cast<const ushort2*>(zn + (size_t)row * D)[lane];
    const float2 tv = reinterpret_cast<const float2*>(t + (size_t)c * D)[lane];
    __hip_bfloat16 h0, h1;
    *reinterpret_cast<ushort*>(&h0) = u.x;
    *reinterpret_cast<ushort*>(&h1) = u.y;
    float dot = __bfloat162float(h0) * tv.x + __bfloat162float(h1) * tv.y;
    #pragma unroll
    for (int m = 1; m < 64; m <<= 1) dot += __shfl_xor(dot, m);
    float zs = (lane < JC) ? pZ[lane * N + row] : 0.0f;
    #pragma unroll
    for (int m = 1; m < JC; m <<= 1) zs += __shfl_xor(zs, m);
    if (lane == 0) {
        const float di = dii[row];
        const float zc = zs - EXP2(fmaf(di, K1F, K0F));   // remove self term
        const float cn = cnt[c] - 1.0f;                   // exclude self
        const float S  = dot - di;                        // exclude self
        const float denom = fmaxf(cn, 1.0f);
        const float lse   = 10.0f + logf(zc);
        out[row] = -(10.0f * S) / denom + (cn > 0.5f ? lse : 0.0f);
    }
}

extern "C" void kernel_launch(void* const* d_in, const int* in_sizes, int n_in,
                              void* d_out, int out_size, void* d_ws, size_t ws_size,
                              hipStream_t stream) {
    const float* z = (const float*)d_in[0];
    const int*   y = (const int*)d_in[1];
    float* out = (float*)d_out;

    // ws layout (~9.3 MB)
    ushort* zn    = (ushort*)d_ws;                                  // 2 MB
    float*  dii   = (float*)((char*)d_ws + (size_t)N * D * 2);      // 32 KB
    float*  tpart = dii + N;                                        // 6.55 MB
    float*  cpart = tpart + (size_t)LCH * NLBL * D;                 // 51.2 KB
    float*  t     = cpart + (size_t)LCH * NLBL;                     // 51.2 KB
    float*  cnt   = t + (size_t)NLBL * D;                           // 400 B
    float*  pZ    = cnt + NLBL;                                     // 512 KB

    znorm_kernel<<<N / 4, 256, 0, stream>>>(z, zn, dii);
    labelsum_kernel<<<LCH, 256, 0, stream>>>(zn, y, tpart, cpart);
    reduce_t_kernel<<<NLBL * D / 64 + 1, 256, 0, stream>>>(tpart, cpart, t, cnt);
    supcon_main<<<NRB * JC, 256, 0, stream>>>(zn, pZ);
    supcon_finalize<<<N / 4, 256, 0, stream>>>(zn, y, pZ, dii, t, cnt, out);
}

// Round 7
// 55.262 us; speedup vs baseline: 2.2515x; 2.2515x over previous
//
#include <hip/hip_runtime.h>
#include <hip/hip_bf16.h>

#define N 8192
#define D 128
#define JC 32                // j-chunks
#define JCH (N / JC)         // 256 cols per chunk
#define WROWS 128            // rows per wave (8 M-tiles, a[8][4] -> AGPRs)
#define NRG (N / WROWS)      // 64 row-groups
#define NLBL 100             // labels in [0,100)
#define LCH 128              // labelsum blocks
#define LR 64                // rows per labelsum block

#define K1F 14.426950408889634f    // 10 * log2(e)
#define K0F (-14.426950408889634f)

#if __has_builtin(__builtin_amdgcn_exp2f)
#define EXP2(x) __builtin_amdgcn_exp2f(x)
#else
#define EXP2(x) exp2f(x)
#endif

typedef __attribute__((ext_vector_type(8))) short bf16x8;
typedef __attribute__((ext_vector_type(4))) float f32x4;

// ---------------- Stage 0: row-normalize z -> bf16 zn, plus self-dot d_ii ----
__global__ __launch_bounds__(256) void znorm_kernel(const float* __restrict__ z,
                                                    ushort* __restrict__ zn,
                                                    float* __restrict__ dii) {
    const int wid  = threadIdx.x >> 6;
    const int lane = threadIdx.x & 63;
    const int row  = blockIdx.x * 4 + wid;       // grid = N/4 blocks
    const float2 v = reinterpret_cast<const float2*>(z + (size_t)row * D)[lane];
    float ss = v.x * v.x + v.y * v.y;
    #pragma unroll
    for (int m = 1; m < 64; m <<= 1) ss += __shfl_xor(ss, m);
    const float inv = 1.0f / fmaxf(sqrtf(ss), 1e-8f);
    __hip_bfloat16 b0 = __float2bfloat16(v.x * inv);
    __hip_bfloat16 b1 = __float2bfloat16(v.y * inv);
    ushort2 o;
    o.x = *reinterpret_cast<ushort*>(&b0);
    o.y = *reinterpret_cast<ushort*>(&b1);
    reinterpret_cast<ushort2*>(zn + (size_t)row * D)[lane] = o;
    const float f0 = __bfloat162float(b0), f1 = __bfloat162float(b1);
    float s2 = f0 * f0 + f1 * f1;
    #pragma unroll
    for (int m = 1; m < 64; m <<= 1) s2 += __shfl_xor(s2, m);
    if (lane == 0) dii[row] = s2;
}

// ---------------- Stage 0b: per-label sums + histogram (deterministic) ------
__global__ __launch_bounds__(256) void labelsum_kernel(const ushort* __restrict__ zn,
                                                       const int* __restrict__ y,
                                                       float* __restrict__ tpart,
                                                       float* __restrict__ cpart) {
    __shared__ float tl[2][NLBL][D];   // 102.4 KB
    __shared__ float ch[2][128];
    __shared__ int   ly[LR];
    const int h = threadIdx.x >> 7;
    const int d = threadIdx.x & 127;
    for (int c = 0; c < NLBL; ++c) tl[h][c][d] = 0.0f;
    if (threadIdx.x < LR) ly[threadIdx.x] = y[blockIdx.x * LR + threadIdx.x];
    __syncthreads();
    const int j0 = blockIdx.x * LR + h * 32;
    float cl = 0.0f;
    for (int j = 0; j < 32; ++j) {
        const int c = ly[h * 32 + j];
        __hip_bfloat16 hb;
        *reinterpret_cast<ushort*>(&hb) = zn[(size_t)(j0 + j) * D + d];
        tl[h][c][d] += __bfloat162float(hb);      // exclusive column: no race
        cl += (c == d) ? 1.0f : 0.0f;
    }
    ch[h][d] = cl;
    __syncthreads();
    const float* t0 = &tl[0][0][0];
    for (int idx = threadIdx.x; idx < NLBL * D; idx += 256)
        tpart[(size_t)blockIdx.x * NLBL * D + idx] = t0[idx] + t0[NLBL * D + idx];
    if (threadIdx.x < NLBL)
        cpart[blockIdx.x * NLBL + threadIdx.x] = ch[0][threadIdx.x] + ch[1][threadIdx.x];
}

// ---------------- Stage 0c: reduce partials (parallel over outputs) ---------
__global__ __launch_bounds__(256) void reduce_t_kernel(const float* __restrict__ tpart,
                                                       const float* __restrict__ cpart,
                                                       float* __restrict__ t,
                                                       float* __restrict__ cnt) {
    if (blockIdx.x < NLBL * D / 64) {
        __shared__ float s4[4][64];
        const int o  = blockIdx.x * 64 + (threadIdx.x & 63);
        const int sl = threadIdx.x >> 6;           // 4 slices x 32 chunks
        float s = 0.0f;
        #pragma unroll 8
        for (int b = sl * (LCH / 4); b < (sl + 1) * (LCH / 4); ++b)
            s += tpart[(size_t)b * NLBL * D + o];
        s4[sl][threadIdx.x & 63] = s;
        __syncthreads();
        if (threadIdx.x < 64)
            t[blockIdx.x * 64 + threadIdx.x] = s4[0][threadIdx.x] + s4[1][threadIdx.x] +
                                               s4[2][threadIdx.x] + s4[3][threadIdx.x];
    } else {
        const int c = threadIdx.x;
        if (c < NLBL) {
            float s = 0.0f;
            for (int b = 0; b < LCH; ++b) s += cpart[b * NLBL + c];
            cnt[c] = s;
        }
    }
}

// ---------------- Stage 1: streaming MFMA, high per-wave intensity ----------
// 2048 fully independent waves (no LDS, no barriers): wave = 128 rows x 256
// cols. a[8][4] (128 regs) goes to the AGPR file (R4 evidence); per 16-col
// iter: 4 B-loads feed 32 MFMAs (~620 SIMD-cyc) -> latency covered even at
// 2 waves/SIMD. Ping-pong B double buffer as in R2/R4.
__global__ __launch_bounds__(256) void supcon_main(const ushort* __restrict__ zn,
                                                   float* __restrict__ pZ) {
    const int wid  = threadIdx.x >> 6;
    const int lane = threadIdx.x & 63;
    const int g    = lane >> 4;      // 0..3
    const int lj   = lane & 15;
    const int gw   = blockIdx.x * 4 + wid;       // 0..2047
    const int rowGrp = gw >> 5;                  // 64 row-groups (block-shared)
    const int chunk  = gw & 31;                  // 32 col-chunks
    const int rowBase = rowGrp * WROWS;
    const int j0 = chunk * JCH;

    // B column stream: 16 cols per iter
    const ushort* jp = zn + (size_t)(j0 + lj) * D + g * 8;
    bf16x8 b0[4], b1[4];
    #pragma unroll
    for (int s = 0; s < 4; ++s) b0[s] = *reinterpret_cast<const bf16x8*>(jp + s * 32);

    // A fragments: 8 M-tiles x 4 K-steps (128 regs -> AGPR file)
    bf16x8 a[8][4];
    #pragma unroll
    for (int m = 0; m < 8; ++m) {
        const ushort* rp = zn + (size_t)(rowBase + m * 16 + lj) * D;
        #pragma unroll
        for (int s = 0; s < 4; ++s)
            a[m][s] = *reinterpret_cast<const bf16x8*>(rp + s * 32 + g * 8);
    }

    float Z[8][4];
    #pragma unroll
    for (int m = 0; m < 8; ++m)
        #pragma unroll
        for (int r = 0; r < 4; ++r) Z[m][r] = 0.0f;

    const f32x4 zero4 = {0.f, 0.f, 0.f, 0.f};
    auto compute = [&](const bf16x8* B) {
        #pragma unroll
        for (int m = 0; m < 8; ++m) {
            f32x4 acc = zero4;
            #pragma unroll
            for (int s = 0; s < 4; ++s)
                acc = __builtin_amdgcn_mfma_f32_16x16x32_bf16(a[m][s], B[s], acc, 0, 0, 0);
            #pragma unroll
            for (int r = 0; r < 4; ++r)
                Z[m][r] += EXP2(fmaf(acc[r], K1F, K0F));   // exp(10*dot - 10)
        }
    };

    const int NIT = JCH / 16;        // 16 iterations, 16 cols each
    #pragma unroll 1
    for (int it = 0; it < NIT; it += 2) {
        const ushort* jp1 = jp + 16 * D;             // tile it+1
        #pragma unroll
        for (int s = 0; s < 4; ++s) b1[s] = *reinterpret_cast<const bf16x8*>(jp1 + s * 32);
        compute(b0);
        if (it + 2 < NIT) {
            const ushort* jp2 = jp + 32 * D;         // tile it+2
            #pragma unroll
            for (int s = 0; s < 4; ++s) b0[s] = *reinterpret_cast<const bf16x8*>(jp2 + s * 32);
        }
        compute(b1);
        jp += 32 * D;
    }

    // sum the 16 cols within each lane group
    #pragma unroll
    for (int m = 0; m < 8; ++m)
        #pragma unroll
        for (int r = 0; r < 4; ++r)
            #pragma unroll
            for (int mk = 1; mk < 16; mk <<= 1)
                Z[m][r] += __shfl_xor(Z[m][r], mk);

    if (lj == 0) {
        #pragma unroll
        for (int m = 0; m < 8; ++m)
            #pragma unroll
            for (int r = 0; r < 4; ++r)
                pZ[chunk * N + rowBase + m * 16 + g * 4 + r] = Z[m][r];
    }
}

// ---------------- Stage 2: finalize loss ----------------
__global__ __launch_bounds__(256) void supcon_finalize(const ushort* __restrict__ zn,
                                                       const int* __restrict__ y,
                                                       const float* __restrict__ pZ,
                                                       const float* __restrict__ dii,
                                                       const float* __restrict__ t,
                                                       const float* __restrict__ cnt,
                                                       float* __restrict__ out) {
    const int wid  = threadIdx.x >> 6;
    const int lane = threadIdx.x & 63;
    const int row  = blockIdx.x * 4 + wid;
    const int c    = y[row];
    const ushort2 u = reinterpret_cast<const ushort2*>(zn + (size_t)row * D)[lane];
    const float2 tv = reinterpret_cast<const float2*>(t + (size_t)c * D)[lane];
    __hip_bfloat16 h0, h1;
    *reinterpret_cast<ushort*>(&h0) = u.x;
    *reinterpret_cast<ushort*>(&h1) = u.y;
    float dot = __bfloat162float(h0) * tv.x + __bfloat162float(h1) * tv.y;
    #pragma unroll
    for (int m = 1; m < 64; m <<= 1) dot += __shfl_xor(dot, m);
    float zs = (lane < JC) ? pZ[lane * N + row] : 0.0f;
    #pragma unroll
    for (int m = 1; m < JC; m <<= 1) zs += __shfl_xor(zs, m);
    if (lane == 0) {
        const float di = dii[row];
        const float zc = zs - EXP2(fmaf(di, K1F, K0F));   // remove self term
        const float cn = cnt[c] - 1.0f;                   // exclude self
        const float S  = dot - di;                        // exclude self
        const float denom = fmaxf(cn, 1.0f);
        const float lse   = 10.0f + logf(zc);
        out[row] = -(10.0f * S) / denom + (cn > 0.5f ? lse : 0.0f);
    }
}

extern "C" void kernel_launch(void* const* d_in, const int* in_sizes, int n_in,
                              void* d_out, int out_size, void* d_ws, size_t ws_size,
                              hipStream_t stream) {
    const float* z = (const float*)d_in[0];
    const int*   y = (const int*)d_in[1];
    float* out = (float*)d_out;

    // ws layout (~9.7 MB)
    ushort* zn    = (ushort*)d_ws;                                  // 2 MB
    float*  dii   = (float*)((char*)d_ws + (size_t)N * D * 2);      // 32 KB
    float*  tpart = dii + N;                                        // 6.55 MB
    float*  cpart = tpart + (size_t)LCH * NLBL * D;                 // 51.2 KB
    float*  t     = cpart + (size_t)LCH * NLBL;                     // 51.2 KB
    float*  cnt   = t + (size_t)NLBL * D;                           // 400 B
    float*  pZ    = cnt + NLBL;                                     // 1 MB

    znorm_kernel<<<N / 4, 256, 0, stream>>>(z, zn, dii);
    labelsum_kernel<<<LCH, 256, 0, stream>>>(zn, y, tpart, cpart);
    reduce_t_kernel<<<NLBL * D / 64 + 1, 256, 0, stream>>>(tpart, cpart, t, cnt);
    supcon_main<<<(NRG * JC) / 4, 256, 0, stream>>>(zn, pZ);
    supcon_finalize<<<N / 4, 256, 0, stream>>>(zn, y, pZ, dii, t, cnt, out);
}

// Round 8
// 50.471 us; speedup vs baseline: 2.4653x; 1.0949x over previous
//
#include <hip/hip_runtime.h>
#include <hip/hip_bf16.h>

#define N 8192
#define D 128
#define JC 32                // j-chunks
#define JCH (N / JC)         // 256 cols per chunk
#define WROWS 128            // rows per wave (8 M-tiles, a[8][4] -> AGPRs)
#define NRG (N / WROWS)      // 64 row-groups
#define NLBL 100             // labels in [0,100)
#define LCH 128              // labelsum blocks
#define LR 64                // rows per labelsum block

#define K1F 14.426950408889634f    // 10 * log2(e)
#define K0F (-14.426950408889634f)

#if __has_builtin(__builtin_amdgcn_exp2f)
#define EXP2(x) __builtin_amdgcn_exp2f(x)
#else
#define EXP2(x) exp2f(x)
#endif

typedef __attribute__((ext_vector_type(8))) short bf16x8;
typedef __attribute__((ext_vector_type(4))) float f32x4;

// ---------------- Stage 0: row-normalize z -> bf16 zn, plus self-dot d_ii ----
__global__ __launch_bounds__(256) void znorm_kernel(const float* __restrict__ z,
                                                    ushort* __restrict__ zn,
                                                    float* __restrict__ dii) {
    const int wid  = threadIdx.x >> 6;
    const int lane = threadIdx.x & 63;
    const int row  = blockIdx.x * 4 + wid;       // grid = N/4 blocks
    const float2 v = reinterpret_cast<const float2*>(z + (size_t)row * D)[lane];
    float ss = v.x * v.x + v.y * v.y;
    #pragma unroll
    for (int m = 1; m < 64; m <<= 1) ss += __shfl_xor(ss, m);
    const float inv = 1.0f / fmaxf(sqrtf(ss), 1e-8f);
    __hip_bfloat16 b0 = __float2bfloat16(v.x * inv);
    __hip_bfloat16 b1 = __float2bfloat16(v.y * inv);
    ushort2 o;
    o.x = *reinterpret_cast<ushort*>(&b0);
    o.y = *reinterpret_cast<ushort*>(&b1);
    reinterpret_cast<ushort2*>(zn + (size_t)row * D)[lane] = o;
    const float f0 = __bfloat162float(b0), f1 = __bfloat162float(b1);
    float s2 = f0 * f0 + f1 * f1;
    #pragma unroll
    for (int m = 1; m < 64; m <<= 1) s2 += __shfl_xor(s2, m);
    if (lane == 0) dii[row] = s2;
}

// ---------------- Stage 0b: per-label sums + histogram (deterministic) ------
__global__ __launch_bounds__(256) void labelsum_kernel(const ushort* __restrict__ zn,
                                                       const int* __restrict__ y,
                                                       float* __restrict__ tpart,
                                                       float* __restrict__ cpart) {
    __shared__ float tl[2][NLBL][D];   // 102.4 KB
    __shared__ float ch[2][128];
    __shared__ int   ly[LR];
    const int h = threadIdx.x >> 7;
    const int d = threadIdx.x & 127;
    for (int c = 0; c < NLBL; ++c) tl[h][c][d] = 0.0f;
    if (threadIdx.x < LR) ly[threadIdx.x] = y[blockIdx.x * LR + threadIdx.x];
    __syncthreads();
    const int j0 = blockIdx.x * LR + h * 32;
    float cl = 0.0f;
    for (int j = 0; j < 32; ++j) {
        const int c = ly[h * 32 + j];
        __hip_bfloat16 hb;
        *reinterpret_cast<ushort*>(&hb) = zn[(size_t)(j0 + j) * D + d];
        tl[h][c][d] += __bfloat162float(hb);      // exclusive column: no race
        cl += (c == d) ? 1.0f : 0.0f;
    }
    ch[h][d] = cl;
    __syncthreads();
    const float* t0 = &tl[0][0][0];
    for (int idx = threadIdx.x; idx < NLBL * D; idx += 256)
        tpart[(size_t)blockIdx.x * NLBL * D + idx] = t0[idx] + t0[NLBL * D + idx];
    if (threadIdx.x < NLBL)
        cpart[blockIdx.x * NLBL + threadIdx.x] = ch[0][threadIdx.x] + ch[1][threadIdx.x];
}

// ---------------- Stage 0c: reduce partials (parallel over outputs) ---------
__global__ __launch_bounds__(256) void reduce_t_kernel(const float* __restrict__ tpart,
                                                       const float* __restrict__ cpart,
                                                       float* __restrict__ t,
                                                       float* __restrict__ cnt) {
    if (blockIdx.x < NLBL * D / 64) {
        __shared__ float s4[4][64];
        const int o  = blockIdx.x * 64 + (threadIdx.x & 63);
        const int sl = threadIdx.x >> 6;           // 4 slices x 32 chunks
        float s = 0.0f;
        #pragma unroll 8
        for (int b = sl * (LCH / 4); b < (sl + 1) * (LCH / 4); ++b)
            s += tpart[(size_t)b * NLBL * D + o];
        s4[sl][threadIdx.x & 63] = s;
        __syncthreads();
        if (threadIdx.x < 64)
            t[blockIdx.x * 64 + threadIdx.x] = s4[0][threadIdx.x] + s4[1][threadIdx.x] +
                                               s4[2][threadIdx.x] + s4[3][threadIdx.x];
    } else {
        const int c = threadIdx.x;
        if (c < NLBL) {
            float s = 0.0f;
            for (int b = 0; b < LCH; ++b) s += cpart[b * NLBL + c];
            cnt[c] = s;
        }
    }
}

// ---------------- Stage 1: streaming MFMA, high per-wave intensity ----------
// 2048 fully independent waves (no LDS, no barriers): wave = 128 rows x 256
// cols. __launch_bounds__(256,2) caps total regs (unified VGPR+AGPR) at 256
// -> a[8][4]=128 AGPR + ~110 arch fits, 2 waves/SIMD resident (R7 was 260
// regs -> 1 wave/SIMD, MfmaUtil 16%). Ping-pong B double buffer.
__global__ __launch_bounds__(256, 2) void supcon_main(const ushort* __restrict__ zn,
                                                      float* __restrict__ pZ) {
    const int wid  = threadIdx.x >> 6;
    const int lane = threadIdx.x & 63;
    const int g    = lane >> 4;      // 0..3
    const int lj   = lane & 15;
    const int gw   = blockIdx.x * 4 + wid;       // 0..2047
    const int rowGrp = gw >> 5;                  // 64 row-groups (block-shared)
    const int chunk  = gw & 31;                  // 32 col-chunks
    const int rowBase = rowGrp * WROWS;
    const int j0 = chunk * JCH;

    // B column stream: 16 cols per iter
    const ushort* jp = zn + (size_t)(j0 + lj) * D + g * 8;
    bf16x8 b0[4], b1[4];
    #pragma unroll
    for (int s = 0; s < 4; ++s) b0[s] = *reinterpret_cast<const bf16x8*>(jp + s * 32);

    // A fragments: 8 M-tiles x 4 K-steps (128 regs -> AGPR file)
    bf16x8 a[8][4];
    #pragma unroll
    for (int m = 0; m < 8; ++m) {
        const ushort* rp = zn + (size_t)(rowBase + m * 16 + lj) * D;
        #pragma unroll
        for (int s = 0; s < 4; ++s)
            a[m][s] = *reinterpret_cast<const bf16x8*>(rp + s * 32 + g * 8);
    }

    float Z[8][4];
    #pragma unroll
    for (int m = 0; m < 8; ++m)
        #pragma unroll
        for (int r = 0; r < 4; ++r) Z[m][r] = 0.0f;

    const f32x4 zero4 = {0.f, 0.f, 0.f, 0.f};
    auto compute = [&](const bf16x8* B) {
        #pragma unroll
        for (int m = 0; m < 8; ++m) {
            f32x4 acc = zero4;
            #pragma unroll
            for (int s = 0; s < 4; ++s)
                acc = __builtin_amdgcn_mfma_f32_16x16x32_bf16(a[m][s], B[s], acc, 0, 0, 0);
            #pragma unroll
            for (int r = 0; r < 4; ++r)
                Z[m][r] += EXP2(fmaf(acc[r], K1F, K0F));   // exp(10*dot - 10)
        }
    };

    const int NIT = JCH / 16;        // 16 iterations, 16 cols each
    #pragma unroll 1
    for (int it = 0; it < NIT; it += 2) {
        const ushort* jp1 = jp + 16 * D;             // tile it+1
        #pragma unroll
        for (int s = 0; s < 4; ++s) b1[s] = *reinterpret_cast<const bf16x8*>(jp1 + s * 32);
        compute(b0);
        if (it + 2 < NIT) {
            const ushort* jp2 = jp + 32 * D;         // tile it+2
            #pragma unroll
            for (int s = 0; s < 4; ++s) b0[s] = *reinterpret_cast<const bf16x8*>(jp2 + s * 32);
        }
        compute(b1);
        jp += 32 * D;
    }

    // sum the 16 cols within each lane group
    #pragma unroll
    for (int m = 0; m < 8; ++m)
        #pragma unroll
        for (int r = 0; r < 4; ++r)
            #pragma unroll
            for (int mk = 1; mk < 16; mk <<= 1)
                Z[m][r] += __shfl_xor(Z[m][r], mk);

    if (lj == 0) {
        #pragma unroll
        for (int m = 0; m < 8; ++m)
            #pragma unroll
            for (int r = 0; r < 4; ++r)
                pZ[chunk * N + rowBase + m * 16 + g * 4 + r] = Z[m][r];
    }
}

// ---------------- Stage 2: finalize loss ----------------
__global__ __launch_bounds__(256) void supcon_finalize(const ushort* __restrict__ zn,
                                                       const int* __restrict__ y,
                                                       const float* __restrict__ pZ,
                                                       const float* __restrict__ dii,
                                                       const float* __restrict__ t,
                                                       const float* __restrict__ cnt,
                                                       float* __restrict__ out) {
    const int wid  = threadIdx.x >> 6;
    const int lane = threadIdx.x & 63;
    const int row  = blockIdx.x * 4 + wid;
    const int c    = y[row];
    const ushort2 u = reinterpret_cast<const ushort2*>(zn + (size_t)row * D)[lane];
    const float2 tv = reinterpret_cast<const float2*>(t + (size_t)c * D)[lane];
    __hip_bfloat16 h0, h1;
    *reinterpret_cast<ushort*>(&h0) = u.x;
    *reinterpret_cast<ushort*>(&h1) = u.y;
    float dot = __bfloat162float(h0) * tv.x + __bfloat162float(h1) * tv.y;
    #pragma unroll
    for (int m = 1; m < 64; m <<= 1) dot += __shfl_xor(dot, m);
    float zs = (lane < JC) ? pZ[lane * N + row] : 0.0f;
    #pragma unroll
    for (int m = 1; m < JC; m <<= 1) zs += __shfl_xor(zs, m);
    if (lane == 0) {
        const float di = dii[row];
        const float zc = zs - EXP2(fmaf(di, K1F, K0F));   // remove self term
        const float cn = cnt[c] - 1.0f;                   // exclude self
        const float S  = dot - di;                        // exclude self
        const float denom = fmaxf(cn, 1.0f);
        const float lse   = 10.0f + logf(zc);
        out[row] = -(10.0f * S) / denom + (cn > 0.5f ? lse : 0.0f);
    }
}

extern "C" void kernel_launch(void* const* d_in, const int* in_sizes, int n_in,
                              void* d_out, int out_size, void* d_ws, size_t ws_size,
                              hipStream_t stream) {
    const float* z = (const float*)d_in[0];
    const int*   y = (const int*)d_in[1];
    float* out = (float*)d_out;

    // ws layout (~9.7 MB)
    ushort* zn    = (ushort*)d_ws;                                  // 2 MB
    float*  dii   = (float*)((char*)d_ws + (size_t)N * D * 2);      // 32 KB
    float*  tpart = dii + N;                                        // 6.55 MB
    float*  cpart = tpart + (size_t)LCH * NLBL * D;                 // 51.2 KB
    float*  t     = cpart + (size_t)LCH * NLBL;                     // 51.2 KB
    float*  cnt   = t + (size_t)NLBL * D;                           // 400 B
    float*  pZ    = cnt + NLBL;                                     // 1 MB

    znorm_kernel<<<N / 4, 256, 0, stream>>>(z, zn, dii);
    labelsum_kernel<<<LCH, 256, 0, stream>>>(zn, y, tpart, cpart);
    reduce_t_kernel<<<NLBL * D / 64 + 1, 256, 0, stream>>>(tpart, cpart, t, cnt);
    supcon_main<<<(NRG * JC) / 4, 256, 0, stream>>>(zn, pZ);
    supcon_finalize<<<N / 4, 256, 0, stream>>>(zn, y, pZ, dii, t, cnt, out);
}